// Round 20
// baseline (418.563 us; speedup 1.0000x reference)
//
#include <hip/hip_runtime.h>
#include <hip/hip_bf16.h>

typedef short short8 __attribute__((ext_vector_type(8)));
typedef short short4v __attribute__((ext_vector_type(4)));
typedef float floatx4 __attribute__((ext_vector_type(4)));
typedef unsigned int uint4v __attribute__((ext_vector_type(4)));

constexpr int Bc = 2, Sc = 4096, Dc = 512, Hc = 8, DKc = 64;
constexpr int Mc = Bc * Sc;  // 8192

static __device__ __forceinline__ unsigned short f2bf(float f) {
  unsigned int u = __builtin_bit_cast(unsigned int, f);
  unsigned int rb = ((u >> 16) & 1u) + 0x7fffu;
  return (unsigned short)((u + rb) >> 16);
}
// hardware packed f32x2 -> bf16x2 (RNE), 1 instruction
static __device__ __forceinline__ unsigned int cvt_pk_bf16(float lo, float hi) {
  unsigned int r;
  asm("v_cvt_pk_bf16_f32 %0, %1, %2" : "=v"(r) : "v"(lo), "v"(hi));
  return r;
}
// 2^x, 1 instruction
static __device__ __forceinline__ float exp2_fast(float x) {
  float r;
  asm("v_exp_f32 %0, %1" : "=v"(r) : "v"(x));
  return r;
}
// NOTE (R9-R11): v_permlane16/32_swap_b32 BANNED (3 correctness failures).
// NOTE (R17): smaller attn blocks for occupancy REGRESS (work per-cell 2x).

// ---------------- GEMM body: Y[M,N] = X[M,K] @ W[N,K]^T ----------------------
// Double-buffered; one barrier per K-iter; W_F32 casts weights during staging.
// VT_OUT writes the V projection as key-permuted transpose vt (fused).
template <int IN_F32, int OUT_F32, int W_F32, int VT_OUT>
static __device__ __forceinline__ void gemm_body(
    const void* __restrict__ Xv, const void* __restrict__ Wp,
    void* __restrict__ Yv, const int N, const int K) {
  constexpr int BM = 128, BN = 64, BK = 32, LDP = 40;
  __shared__ unsigned short As[2][BM * LDP];
  __shared__ unsigned short Bs[2][BN * LDP];
  const int tid = threadIdx.x;
  const int lane = tid & 63, wid = tid >> 6;
  const int wm = wid >> 1, wn = wid & 1;
  const int bm = blockIdx.y * BM, bn = blockIdx.x * BN;
  const int rq = lane & 15, lg = lane >> 4, kk8 = lg * 8;
  const int sr = tid >> 1, sc = (tid & 1) * 16;
  const int brow = tid >> 2, bc8 = (tid & 3) * 8;

  floatx4 acc[4][2] = {};

  float a32[16];
  short8 a16[2];
  float b32[8];
  short8 b16;

  auto load_tile = [&](int k0) {
    if (IN_F32) {
      const float* src = (const float*)Xv + (size_t)(bm + sr) * K + k0 + sc;
#pragma unroll
      for (int i = 0; i < 4; ++i) {
        float4 v = *(const float4*)(src + i * 4);
        a32[4 * i + 0] = v.x; a32[4 * i + 1] = v.y;
        a32[4 * i + 2] = v.z; a32[4 * i + 3] = v.w;
      }
    } else {
      const unsigned short* src =
          (const unsigned short*)Xv + (size_t)(bm + sr) * K + k0 + sc;
      a16[0] = *(const short8*)src;
      a16[1] = *(const short8*)(src + 8);
    }
    if (W_F32) {
      const float* wsrc = (const float*)Wp + (size_t)(bn + brow) * K + k0 + bc8;
#pragma unroll
      for (int i = 0; i < 2; ++i) {
        float4 v = *(const float4*)(wsrc + i * 4);
        b32[4 * i + 0] = v.x; b32[4 * i + 1] = v.y;
        b32[4 * i + 2] = v.z; b32[4 * i + 3] = v.w;
      }
    } else {
      b16 = *(const short8*)((const unsigned short*)Wp +
                             (size_t)(bn + brow) * K + k0 + bc8);
    }
  };
  auto store_tile = [&](int bf) {
    if (IN_F32) {
      unsigned int t2[8];
#pragma unroll
      for (int i = 0; i < 8; ++i) t2[i] = cvt_pk_bf16(a32[2 * i], a32[2 * i + 1]);
      uint4v u0 = {t2[0], t2[1], t2[2], t2[3]};
      uint4v u1 = {t2[4], t2[5], t2[6], t2[7]};
      *(uint4v*)&As[bf][sr * LDP + sc] = u0;
      *(uint4v*)&As[bf][sr * LDP + sc + 8] = u1;
    } else {
      *(short8*)&As[bf][sr * LDP + sc] = a16[0];
      *(short8*)&As[bf][sr * LDP + sc + 8] = a16[1];
    }
    if (W_F32) {
      unsigned int t2[4];
#pragma unroll
      for (int i = 0; i < 4; ++i) t2[i] = cvt_pk_bf16(b32[2 * i], b32[2 * i + 1]);
      uint4v u = {t2[0], t2[1], t2[2], t2[3]};
      *(uint4v*)&Bs[bf][brow * LDP + bc8] = u;
    } else {
      *(short8*)&Bs[bf][brow * LDP + bc8] = b16;
    }
  };

  load_tile(0);
  store_tile(0);

  const int NK = K / BK;  // 16
  for (int it = 0; it < NK; ++it) {
    const int cur = it & 1;
    __syncthreads();

    if (it < NK - 1) load_tile((it + 1) * BK);

    short8 af[4], bfr[2];
#pragma unroll
    for (int mi = 0; mi < 4; ++mi)
      af[mi] = *(const short8*)&As[cur][(wm * 64 + mi * 16 + rq) * LDP + kk8];
#pragma unroll
    for (int ni = 0; ni < 2; ++ni)
      bfr[ni] = *(const short8*)&Bs[cur][(wn * 32 + ni * 16 + rq) * LDP + kk8];
#pragma unroll
    for (int mi = 0; mi < 4; ++mi)
#pragma unroll
      for (int ni = 0; ni < 2; ++ni)
        acc[mi][ni] = __builtin_amdgcn_mfma_f32_16x16x32_bf16(
            af[mi], bfr[ni], acc[mi][ni], 0, 0, 0);

    if (it < NK - 1) store_tile(cur ^ 1);
  }

  if (VT_OUT) {
    // fused transpose + sigma-permute epilogue (V projection -> vt).
    __syncthreads();
    unsigned short* T = (unsigned short*)As;  // [64 c][136] shorts
    const int bb = bm >> 12;
    const int sl0 = bm & 4095;
#pragma unroll
    for (int mi = 0; mi < 4; ++mi) {
      const int spb = wm * 64 + (mi >> 1) * 32 + lg * 8 + (mi & 1) * 4;
#pragma unroll
      for (int ni = 0; ni < 2; ++ni) {
        const int c = wn * 32 + ni * 16 + rq;
#pragma unroll
        for (int j = 0; j < 4; ++j)
          T[c * 136 + spb + j] = f2bf(acc[mi][ni][j]);
      }
    }
    __syncthreads();
    const int c = tid >> 2, seg = (tid & 3) * 32;
    unsigned short* dst = (unsigned short*)Yv +
        ((size_t)bb * Dc + bn + c) * Sc + sl0 + seg;
#pragma unroll
    for (int u = 0; u < 4; ++u)
      *(short8*)(dst + u * 8) = *(const short8*)&T[c * 136 + seg + u * 8];
  } else {
#pragma unroll
    for (int mi = 0; mi < 4; ++mi)
#pragma unroll
      for (int ni = 0; ni < 2; ++ni)
#pragma unroll
        for (int j = 0; j < 4; ++j) {
          int r = bm + wm * 64 + mi * 16 + lg * 4 + j;
          int c = bn + wn * 32 + ni * 16 + rq;
          float v = acc[mi][ni][j];
          if (OUT_F32)
            ((float*)Yv)[(size_t)r * N + c] = v;
          else
            ((unsigned short*)Yv)[(size_t)r * N + c] = f2bf(v);
        }
  }
}

// batched Q/K/V projection: blockIdx.z selects input/weight/output.
__global__ __launch_bounds__(256) void gemm_qkv(
    const float* __restrict__ xq, const float* __restrict__ xk,
    const float* __restrict__ xv, const float* __restrict__ wq,
    const float* __restrict__ wk, const float* __restrict__ wv,
    unsigned short* __restrict__ yq, unsigned short* __restrict__ yk,
    unsigned short* __restrict__ vt) {
  const int z = blockIdx.z;
  if (z == 2) {
    gemm_body<1, 0, 1, 1>(xv, wv, vt, Dc, Dc);
  } else {
    const float* X = (z == 0) ? xq : xk;
    const float* W = (z == 0) ? wq : wk;
    unsigned short* Y = (z == 0) ? yq : yk;
    gemm_body<1, 0, 1, 0>(X, W, Y, Dc, Dc);
  }
}

// output projection: bf16 input, f32 weight, f32 output.
__global__ __launch_bounds__(256) void gemm_out(
    const unsigned short* __restrict__ x, const float* __restrict__ w,
    float* __restrict__ y) {
  gemm_body<0, 1, 1, 0>(x, w, y, Dc, Dc);
}

// ---------------- flash attention --------------------------------------------
// R20: ZERO-LDS, BARRIER-FREE main loop. R19's XCD swizzle made K/V fully
// L2-resident (FETCH 69.7->12.3MB), so LDS staging is pure overhead (guide
// Common-mistake #7 / m169). Fragment loads go straight to global: for fixed
// rq, the 4 lg-lanes read one contiguous 64B line -> each wave-load is a
// 16-line gather; the 4 qc-waves per block re-read the same lines via L1.
// K-frags double-buffered in registers (needed at iter start); V-frags loaded
// directly, issued before the softmax VALU chain (~200cy to hide). LDS kept
// only for the final 2-way merge. All other R18/R19 techniques retained.
__global__ __launch_bounds__(512, 4) void attn_fwd(
    const unsigned short* __restrict__ Qp, const unsigned short* __restrict__ Kp,
    const unsigned short* __restrict__ Vtp, unsigned short* __restrict__ Op) {
  __shared__ unsigned char smem[33792];  // merge overlay only

  const int tid = threadIdx.x, lane = tid & 63, wid = tid >> 6;
  const int qc = wid >> 1, kh = wid & 1;
  // XCD swizzle: logical tile from permuted flat id (bijective, 512%8==0)
  const int F = blockIdx.y * 32 + blockIdx.x;   // gridDim.x == 32
  const int L = (F & 7) * 64 + (F >> 3);
  const int bh = L >> 5, qt = L & 31;
  const int b = bh >> 3, h = bh & 7;
  const int q0 = qt * 128 + qc * 32;
  const int rq = lane & 15, lg = lane >> 4, kk8 = lg * 8;

  const unsigned short* Qb = Qp + ((size_t)b * Sc) * Dc + h * DKc;
  const unsigned short* Kb = Kp + ((size_t)b * Sc) * Dc + h * DKc;
  const unsigned short* Vh = Vtp + ((size_t)b * Dc + h * DKc) * Sc;

  // per-wave fragment base pointers (staging XOR cancels out of both paths)
  const unsigned short* Kw = Kb + (size_t)(kh * 32 + rq) * Dc + kk8;
  const unsigned short* Vw = Vh + (size_t)rq * Sc + kh * 32 + kk8;

  // Q as B-fragment: col = lane&15 = q-local, k = (lane>>4)*8+j
  short8 qa[2][2];
#pragma unroll
  for (int qi = 0; qi < 2; ++qi)
#pragma unroll
    for (int c = 0; c < 2; ++c)
      qa[qi][c] = *(const short8*)(Qb + (size_t)(q0 + qi * 16 + rq) * Dc + c * 32 + kk8);

  floatx4 o_acc[2][4] = {};
  floatx4 acc_l[2] = {};              // l via MFMA: row q = qi*16+lg*4+j
  float m_run[2] = {-1e30f, -1e30f};  // per-lane (q = lane&15), log2 domain

  short8 ones;
#pragma unroll
  for (int j = 0; j < 8; ++j) ones[j] = (short)0x3F80;  // bf16 1.0

  const float C2 = 0.18033688f;   // (1/sqrt(64)) * log2(e)
  const float THR = 8.0f;         // defer-max bound: P <= 2^8

  auto load_k = [&](short8 (&ka)[2][2], int k0) {
#pragma unroll
    for (int ks = 0; ks < 2; ++ks)
#pragma unroll
      for (int c = 0; c < 2; ++c)
        ka[ks][c] = *(const short8*)(Kw + (size_t)(k0 + ks * 16) * Dc + c * 32);
  };

  auto compute = [&](short8 (&ka)[2][2], int k0) {
    // V frags issued first: latency hides under QK^T + softmax
    short8 vv[4];
#pragma unroll
    for (int dt = 0; dt < 4; ++dt)
      vv[dt] = *(const short8*)(Vw + (size_t)(dt * 16) * Sc + k0);

    short8 pb_[2];
#pragma unroll
    for (int qi = 0; qi < 2; ++qi) {
      // swapped QK^T: s[ks][j] = S^T[key = k0+kh*32+ks*16+lg*4+j][q = rq]
      floatx4 s[2] = {};
#pragma unroll
      for (int ks = 0; ks < 2; ++ks) {
        s[ks] = __builtin_amdgcn_mfma_f32_16x16x32_bf16(ka[ks][0], qa[qi][0], s[ks], 0, 0, 0);
        s[ks] = __builtin_amdgcn_mfma_f32_16x16x32_bf16(ka[ks][1], qa[qi][1], s[ks], 0, 0, 0);
      }
      // per-lane partial max over own 8 keys: max3-shaped tree
      float t1 = fmaxf(fmaxf(s[0][0], s[0][1]), s[0][2]);
      float t2 = fmaxf(fmaxf(s[0][3], s[1][0]), s[1][1]);
      float t3 = fmaxf(fmaxf(s[1][2], s[1][3]), t1);
      float tp = fmaxf(t3, t2) * C2;

      if (__any(tp > m_run[qi] + THR)) {  // rare: bound would be exceeded
        float tm = tp;
        tm = fmaxf(tm, __shfl_xor(tm, 16, 64));
        tm = fmaxf(tm, __shfl_xor(tm, 32, 64));
        if (__any(tm > m_run[qi])) {
          float mn = fmaxf(m_run[qi], tm);
          float scf = exp2_fast(m_run[qi] - mn);
          m_run[qi] = mn;
          float sc_c[4];
#pragma unroll
          for (int j = 0; j < 4; ++j) sc_c[j] = __shfl(scf, lg * 4 + j, 64);
#pragma unroll
          for (int j = 0; j < 4; ++j) {
            acc_l[qi][j] *= sc_c[j];
#pragma unroll
            for (int dt = 0; dt < 4; ++dt) o_acc[qi][dt][j] *= sc_c[j];
          }
        }
      }

      // P = 2^(s*C2 - m), packed in A-frag slot order (sigma-matched)
      const float lm = m_run[qi];
      unsigned int pw0, pw1, pw2, pw3;
      {
        float p0 = exp2_fast(fmaf(s[0][0], C2, -lm));
        float p1 = exp2_fast(fmaf(s[0][1], C2, -lm));
        float p2 = exp2_fast(fmaf(s[0][2], C2, -lm));
        float p3 = exp2_fast(fmaf(s[0][3], C2, -lm));
        pw0 = cvt_pk_bf16(p0, p1);
        pw1 = cvt_pk_bf16(p2, p3);
      }
      {
        float p0 = exp2_fast(fmaf(s[1][0], C2, -lm));
        float p1 = exp2_fast(fmaf(s[1][1], C2, -lm));
        float p2 = exp2_fast(fmaf(s[1][2], C2, -lm));
        float p3 = exp2_fast(fmaf(s[1][3], C2, -lm));
        pw2 = cvt_pk_bf16(p0, p1);
        pw3 = cvt_pk_bf16(p2, p3);
      }
      uint4v pw = {pw0, pw1, pw2, pw3};
      pb_[qi] = __builtin_bit_cast(short8, pw);
    }

    // PV: A = pb_ (in-register), B = V^T frags; l on the MFMA pipe.
#pragma unroll
    for (int dt = 0; dt < 4; ++dt) {
      o_acc[0][dt] = __builtin_amdgcn_mfma_f32_16x16x32_bf16(pb_[0], vv[dt], o_acc[0][dt], 0, 0, 0);
      o_acc[1][dt] = __builtin_amdgcn_mfma_f32_16x16x32_bf16(pb_[1], vv[dt], o_acc[1][dt], 0, 0, 0);
    }
    acc_l[0] = __builtin_amdgcn_mfma_f32_16x16x32_bf16(pb_[0], ones, acc_l[0], 0, 0, 0);
    acc_l[1] = __builtin_amdgcn_mfma_f32_16x16x32_bf16(pb_[1], ones, acc_l[1], 0, 0, 0);
  };

  // K double-buffered in registers; no barriers, waves fully independent.
  short8 kaA[2][2], kaB[2][2];
  load_k(kaA, 0);
  for (int it = 0; it < 64; it += 2) {
    load_k(kaB, (it + 1) * 64);
    compute(kaA, it * 64);
    if (it + 2 < 64) load_k(kaA, (it + 2) * 64);
    compute(kaB, (it + 1) * 64);
  }

  __syncthreads();  // waves converge before merge overlay
  // ---- 2-way key-half merge (kh=1 publishes, kh=0 combines + writes) ----
  float* MO = (float*)smem;            // [4 qc][32 q][64 dk]
  float* ML = (float*)(smem + 32768);  // [128 q][2] {m, l}
  if (kh == 1) {
#pragma unroll
    for (int qi = 0; qi < 2; ++qi) {
#pragma unroll
      for (int j = 0; j < 4; ++j) {
        int row = qc * 32 + qi * 16 + lg * 4 + j;
        if (rq == 0) ML[row * 2 + 1] = acc_l[qi][j];
#pragma unroll
        for (int dt = 0; dt < 4; ++dt)
          MO[(size_t)row * 64 + dt * 16 + rq] = o_acc[qi][dt][j];
      }
      if (lg == 0) ML[(qc * 32 + qi * 16 + rq) * 2] = m_run[qi];
    }
  }
  __syncthreads();
  if (kh == 0) {
#pragma unroll
    for (int qi = 0; qi < 2; ++qi) {
      float m0c[4];
#pragma unroll
      for (int j = 0; j < 4; ++j) m0c[j] = __shfl(m_run[qi], lg * 4 + j, 64);
#pragma unroll
      for (int j = 0; j < 4; ++j) {
        int row = qc * 32 + qi * 16 + lg * 4 + j;
        int r = q0 + qi * 16 + lg * 4 + j;
        float m1 = ML[row * 2 + 0], l1 = ML[row * 2 + 1];
        float mx = fmaxf(m0c[j], m1);
        float a0 = exp2_fast(m0c[j] - mx), a1 = exp2_fast(m1 - mx);
        float inv = 1.0f / (acc_l[qi][j] * a0 + l1 * a1);
#pragma unroll
        for (int dt = 0; dt < 4; ++dt) {
          float o = (o_acc[qi][dt][j] * a0 + MO[(size_t)row * 64 + dt * 16 + rq] * a1) * inv;
          Op[((size_t)b * Sc + r) * Dc + h * DKc + dt * 16 + rq] = f2bf(o);
        }
      }
    }
  }
}

// ---------------- launcher --------------------------------------------------
extern "C" void kernel_launch(void* const* d_in, const int* in_sizes, int n_in,
                              void* d_out, int out_size, void* d_ws, size_t ws_size,
                              hipStream_t stream) {
  const float* q_in = (const float*)d_in[0];
  const float* k_in = (const float*)d_in[1];
  const float* v_in = (const float*)d_in[2];
  const float* Wq = (const float*)d_in[3];
  const float* Wk = (const float*)d_in[4];
  const float* Wv = (const float*)d_in[5];
  const float* Wo = (const float*)d_in[6];

  unsigned short* qb = (unsigned short*)d_ws;   // [M,D] bf16
  unsigned short* kb = qb + (size_t)Mc * Dc;
  unsigned short* ab = kb + (size_t)Mc * Dc;
  unsigned short* vt = ab + (size_t)Mc * Dc;    // V^T (key-permuted) per b

  // batched Q/K/V projections; V slice writes vt directly (fused transpose)
  dim3 gq(Dc / 64, Mc / 128, 3);  // (8, 64, 3) = 1536 blocks
  gemm_qkv<<<gq, 256, 0, stream>>>(q_in, k_in, v_in, Wq, Wk, Wv, qb, kb, vt);

  dim3 ga(Sc / 128, Bc * Hc);  // (32, 16) = 512 blocks, 512 thr
  attn_fwd<<<ga, 512, 0, stream>>>(qb, kb, vt, ab);

  dim3 gg(Dc / 64, Mc / 128);  // (8, 64)
  gemm_out<<<gg, 256, 0, stream>>>(ab, Wo, (float*)d_out);
}

// Round 21
// 163.076 us; speedup vs baseline: 2.5667x; 2.5667x over previous
//
#include <hip/hip_runtime.h>
#include <hip/hip_bf16.h>

typedef short short8 __attribute__((ext_vector_type(8)));
typedef short short4v __attribute__((ext_vector_type(4)));
typedef float floatx4 __attribute__((ext_vector_type(4)));
typedef unsigned int uint4v __attribute__((ext_vector_type(4)));

constexpr int Bc = 2, Sc = 4096, Dc = 512, Hc = 8, DKc = 64;
constexpr int Mc = Bc * Sc;  // 8192

static __device__ __forceinline__ unsigned short f2bf(float f) {
  unsigned int u = __builtin_bit_cast(unsigned int, f);
  unsigned int rb = ((u >> 16) & 1u) + 0x7fffu;
  return (unsigned short)((u + rb) >> 16);
}
// hardware packed f32x2 -> bf16x2 (RNE), 1 instruction
static __device__ __forceinline__ unsigned int cvt_pk_bf16(float lo, float hi) {
  unsigned int r;
  asm("v_cvt_pk_bf16_f32 %0, %1, %2" : "=v"(r) : "v"(lo), "v"(hi));
  return r;
}
// 2^x, 1 instruction
static __device__ __forceinline__ float exp2_fast(float x) {
  float r;
  asm("v_exp_f32 %0, %1" : "=v"(r) : "v"(x));
  return r;
}
// NOTE (R9-R11): v_permlane16/32_swap_b32 BANNED (3 correctness failures).
// NOTE (R17): smaller attn blocks for occupancy REGRESS (work per-cell 2x).
// NOTE (R20): direct-global fragment loads REGRESS 3.8x — uncoalesced 16-line
// gathers + lambda-array scratch spill (WRITE_SIZE 171MB). LDS staging stays:
// it is what makes the compute-side reads coalesced, independent of L2 fit.

// ---------------- GEMM body: Y[M,N] = X[M,K] @ W[N,K]^T ----------------------
// Double-buffered; one barrier per K-iter; W_F32 casts weights during staging.
// VT_OUT writes the V projection as key-permuted transpose vt (fused).
template <int IN_F32, int OUT_F32, int W_F32, int VT_OUT>
static __device__ __forceinline__ void gemm_body(
    const void* __restrict__ Xv, const void* __restrict__ Wp,
    void* __restrict__ Yv, const int N, const int K) {
  constexpr int BM = 128, BN = 64, BK = 32, LDP = 40;
  __shared__ unsigned short As[2][BM * LDP];
  __shared__ unsigned short Bs[2][BN * LDP];
  const int tid = threadIdx.x;
  const int lane = tid & 63, wid = tid >> 6;
  const int wm = wid >> 1, wn = wid & 1;
  const int bm = blockIdx.y * BM, bn = blockIdx.x * BN;
  const int rq = lane & 15, lg = lane >> 4, kk8 = lg * 8;
  const int sr = tid >> 1, sc = (tid & 1) * 16;
  const int brow = tid >> 2, bc8 = (tid & 3) * 8;

  floatx4 acc[4][2] = {};

  float a32[16];
  short8 a16[2];
  float b32[8];
  short8 b16;

  auto load_tile = [&](int k0) {
    if (IN_F32) {
      const float* src = (const float*)Xv + (size_t)(bm + sr) * K + k0 + sc;
#pragma unroll
      for (int i = 0; i < 4; ++i) {
        float4 v = *(const float4*)(src + i * 4);
        a32[4 * i + 0] = v.x; a32[4 * i + 1] = v.y;
        a32[4 * i + 2] = v.z; a32[4 * i + 3] = v.w;
      }
    } else {
      const unsigned short* src =
          (const unsigned short*)Xv + (size_t)(bm + sr) * K + k0 + sc;
      a16[0] = *(const short8*)src;
      a16[1] = *(const short8*)(src + 8);
    }
    if (W_F32) {
      const float* wsrc = (const float*)Wp + (size_t)(bn + brow) * K + k0 + bc8;
#pragma unroll
      for (int i = 0; i < 2; ++i) {
        float4 v = *(const float4*)(wsrc + i * 4);
        b32[4 * i + 0] = v.x; b32[4 * i + 1] = v.y;
        b32[4 * i + 2] = v.z; b32[4 * i + 3] = v.w;
      }
    } else {
      b16 = *(const short8*)((const unsigned short*)Wp +
                             (size_t)(bn + brow) * K + k0 + bc8);
    }
  };
  auto store_tile = [&](int bf) {
    if (IN_F32) {
      unsigned int t2[8];
#pragma unroll
      for (int i = 0; i < 8; ++i) t2[i] = cvt_pk_bf16(a32[2 * i], a32[2 * i + 1]);
      uint4v u0 = {t2[0], t2[1], t2[2], t2[3]};
      uint4v u1 = {t2[4], t2[5], t2[6], t2[7]};
      *(uint4v*)&As[bf][sr * LDP + sc] = u0;
      *(uint4v*)&As[bf][sr * LDP + sc + 8] = u1;
    } else {
      *(short8*)&As[bf][sr * LDP + sc] = a16[0];
      *(short8*)&As[bf][sr * LDP + sc + 8] = a16[1];
    }
    if (W_F32) {
      unsigned int t2[4];
#pragma unroll
      for (int i = 0; i < 4; ++i) t2[i] = cvt_pk_bf16(b32[2 * i], b32[2 * i + 1]);
      uint4v u = {t2[0], t2[1], t2[2], t2[3]};
      *(uint4v*)&Bs[bf][brow * LDP + bc8] = u;
    } else {
      *(short8*)&Bs[bf][brow * LDP + bc8] = b16;
    }
  };

  load_tile(0);
  store_tile(0);

  const int NK = K / BK;  // 16
  for (int it = 0; it < NK; ++it) {
    const int cur = it & 1;
    __syncthreads();

    if (it < NK - 1) load_tile((it + 1) * BK);

    short8 af[4], bfr[2];
#pragma unroll
    for (int mi = 0; mi < 4; ++mi)
      af[mi] = *(const short8*)&As[cur][(wm * 64 + mi * 16 + rq) * LDP + kk8];
#pragma unroll
    for (int ni = 0; ni < 2; ++ni)
      bfr[ni] = *(const short8*)&Bs[cur][(wn * 32 + ni * 16 + rq) * LDP + kk8];
#pragma unroll
    for (int mi = 0; mi < 4; ++mi)
#pragma unroll
      for (int ni = 0; ni < 2; ++ni)
        acc[mi][ni] = __builtin_amdgcn_mfma_f32_16x16x32_bf16(
            af[mi], bfr[ni], acc[mi][ni], 0, 0, 0);

    if (it < NK - 1) store_tile(cur ^ 1);
  }

  if (VT_OUT) {
    // fused transpose + sigma-permute epilogue (V projection -> vt).
    __syncthreads();
    unsigned short* T = (unsigned short*)As;  // [64 c][136] shorts
    const int bb = bm >> 12;
    const int sl0 = bm & 4095;
#pragma unroll
    for (int mi = 0; mi < 4; ++mi) {
      const int spb = wm * 64 + (mi >> 1) * 32 + lg * 8 + (mi & 1) * 4;
#pragma unroll
      for (int ni = 0; ni < 2; ++ni) {
        const int c = wn * 32 + ni * 16 + rq;
#pragma unroll
        for (int j = 0; j < 4; ++j)
          T[c * 136 + spb + j] = f2bf(acc[mi][ni][j]);
      }
    }
    __syncthreads();
    const int c = tid >> 2, seg = (tid & 3) * 32;
    unsigned short* dst = (unsigned short*)Yv +
        ((size_t)bb * Dc + bn + c) * Sc + sl0 + seg;
#pragma unroll
    for (int u = 0; u < 4; ++u)
      *(short8*)(dst + u * 8) = *(const short8*)&T[c * 136 + seg + u * 8];
  } else {
#pragma unroll
    for (int mi = 0; mi < 4; ++mi)
#pragma unroll
      for (int ni = 0; ni < 2; ++ni)
#pragma unroll
        for (int j = 0; j < 4; ++j) {
          int r = bm + wm * 64 + mi * 16 + lg * 4 + j;
          int c = bn + wn * 32 + ni * 16 + rq;
          float v = acc[mi][ni][j];
          if (OUT_F32)
            ((float*)Yv)[(size_t)r * N + c] = v;
          else
            ((unsigned short*)Yv)[(size_t)r * N + c] = f2bf(v);
        }
  }
}

// batched Q/K/V projection: blockIdx.z selects input/weight/output.
__global__ __launch_bounds__(256) void gemm_qkv(
    const float* __restrict__ xq, const float* __restrict__ xk,
    const float* __restrict__ xv, const float* __restrict__ wq,
    const float* __restrict__ wk, const float* __restrict__ wv,
    unsigned short* __restrict__ yq, unsigned short* __restrict__ yk,
    unsigned short* __restrict__ vt) {
  const int z = blockIdx.z;
  if (z == 2) {
    gemm_body<1, 0, 1, 1>(xv, wv, vt, Dc, Dc);
  } else {
    const float* X = (z == 0) ? xq : xk;
    const float* W = (z == 0) ? wq : wk;
    unsigned short* Y = (z == 0) ? yq : yk;
    gemm_body<1, 0, 1, 0>(X, W, Y, Dc, Dc);
  }
}

// output projection: bf16 input, f32 weight, f32 output.
__global__ __launch_bounds__(256) void gemm_out(
    const unsigned short* __restrict__ x, const float* __restrict__ w,
    float* __restrict__ y) {
  gemm_body<0, 1, 1, 0>(x, w, y, Dc, Dc);
}

// ---------------- flash attention (R19 exact — verified 95.5us) --------------
// 128 q-rows, 8 waves = 4 q-chunks x 2 key-halves; swapped QK^T; defer-max
// THR=8; in-register P via sigma key-permute; l on the MFMA pipe (ones-frag);
// dbuf LDS K/V, 1 barrier/iter, early global-load issue; XCD block swizzle.
__global__ __launch_bounds__(512, 4) void attn_fwd(
    const unsigned short* __restrict__ Qp, const unsigned short* __restrict__ Kp,
    const unsigned short* __restrict__ Vtp, unsigned short* __restrict__ Op) {
  __shared__ unsigned char smem[33792];
  unsigned short* KsB = (unsigned short*)smem;           // [2][4096]
  unsigned short* VsB = (unsigned short*)(smem + 16384); // [2][4096]

  const int tid = threadIdx.x, lane = tid & 63, wid = tid >> 6;
  const int qc = wid >> 1, kh = wid & 1;
  // XCD swizzle: logical tile from permuted flat id (bijective, 512%8==0)
  const int F = blockIdx.y * 32 + blockIdx.x;   // gridDim.x == 32
  const int L = (F & 7) * 64 + (F >> 3);
  const int bh = L >> 5, qt = L & 31;
  const int b = bh >> 3, h = bh & 7;
  const int q0 = qt * 128 + qc * 32;
  const int rq = lane & 15, lg = lane >> 4, kk8 = lg * 8;

  const unsigned short* Qb = Qp + ((size_t)b * Sc) * Dc + h * DKc;
  const unsigned short* Kb = Kp + ((size_t)b * Sc) * Dc + h * DKc;
  const unsigned short* Vh = Vtp + ((size_t)b * Dc + h * DKc) * Sc;

  // Q as B-fragment: col = lane&15 = q-local, k = (lane>>4)*8+j
  short8 qa[2][2];
#pragma unroll
  for (int qi = 0; qi < 2; ++qi)
#pragma unroll
    for (int c = 0; c < 2; ++c)
      qa[qi][c] = *(const short8*)(Qb + (size_t)(q0 + qi * 16 + rq) * Dc + c * 32 + kk8);

  floatx4 o_acc[2][4] = {};
  floatx4 acc_l[2] = {};              // l via MFMA: row q = qi*16+lg*4+j
  float m_run[2] = {-1e30f, -1e30f};  // per-lane (q = lane&15), log2 domain

  short8 ones;
#pragma unroll
  for (int j = 0; j < 8; ++j) ones[j] = (short)0x3F80;  // bf16 1.0

  const float C2 = 0.18033688f;   // (1/sqrt(64)) * log2(e)
  const float THR = 8.0f;         // defer-max bound: P <= 2^8

  // staging: 512 threads stage K[64][64] + V^T[64][64], 16B each, XOR swizzle
  const int sr = tid >> 3, sc8 = (tid & 7) * 8;
  const int st = (sr * 64 + sc8) ^ ((sr & 7) << 3);
  const int sx = (rq & 7) << 3;

  // prologue: tile 0 -> regs -> buf0
  short8 kr = *(const short8*)(Kb + (size_t)sr * Dc + sc8);
  short8 vr = *(const short8*)(Vh + (size_t)sr * Sc + sc8);
  *(short8*)&KsB[st] = kr;
  *(short8*)&VsB[st] = vr;

  for (int it = 0; it < 64; ++it) {
    const int cur = it & 1;
    __syncthreads();  // buf[cur] writes visible; buf[cur^1] reads done

    if (it < 63) {  // issue next tile's global loads; land during compute
      const int kn = (it + 1) * 64;
      kr = *(const short8*)(Kb + (size_t)(kn + sr) * Dc + sc8);
      vr = *(const short8*)(Vh + (size_t)sr * Sc + kn + sc8);
    }

    const unsigned short* Ks = KsB + cur * 4096;
    const unsigned short* Vs = VsB + cur * 4096;

    // K A-frags for this wave's key-half (shared across both q-subtiles)
    short8 ka[2][2];
#pragma unroll
    for (int ks = 0; ks < 2; ++ks)
#pragma unroll
      for (int c = 0; c < 2; ++c) {
        const int row = kh * 32 + ks * 16 + rq;
        ka[ks][c] = *(const short8*)&Ks[(row * 64 + c * 32 + kk8) ^ sx];
      }

    short8 pb_[2];  // per-qi PV A-frags, built fully in-register
#pragma unroll
    for (int qi = 0; qi < 2; ++qi) {
      // swapped QK^T: s[ks][j] = S^T[key = kh*32+ks*16+lg*4+j][q = rq]
      floatx4 s[2] = {};
#pragma unroll
      for (int ks = 0; ks < 2; ++ks) {
        s[ks] = __builtin_amdgcn_mfma_f32_16x16x32_bf16(ka[ks][0], qa[qi][0], s[ks], 0, 0, 0);
        s[ks] = __builtin_amdgcn_mfma_f32_16x16x32_bf16(ka[ks][1], qa[qi][1], s[ks], 0, 0, 0);
      }
      // per-lane partial max over own 8 keys: max3-shaped tree
      float t1 = fmaxf(fmaxf(s[0][0], s[0][1]), s[0][2]);
      float t2 = fmaxf(fmaxf(s[0][3], s[1][0]), s[1][1]);
      float t3 = fmaxf(fmaxf(s[1][2], s[1][3]), t1);
      float tp = fmaxf(t3, t2) * C2;

      if (__any(tp > m_run[qi] + THR)) {  // rare: bound would be exceeded
        float tm = tp;
        tm = fmaxf(tm, __shfl_xor(tm, 16, 64));
        tm = fmaxf(tm, __shfl_xor(tm, 32, 64));
        if (__any(tm > m_run[qi])) {
          float mn = fmaxf(m_run[qi], tm);
          float scf = exp2_fast(m_run[qi] - mn);
          m_run[qi] = mn;
          float sc_c[4];
#pragma unroll
          for (int j = 0; j < 4; ++j) sc_c[j] = __shfl(scf, lg * 4 + j, 64);
#pragma unroll
          for (int j = 0; j < 4; ++j) {
            acc_l[qi][j] *= sc_c[j];
#pragma unroll
            for (int dt = 0; dt < 4; ++dt) o_acc[qi][dt][j] *= sc_c[j];
          }
        }
      }

      // P = 2^(s*C2 - m), packed in A-frag slot order (sigma-matched)
      const float lm = m_run[qi];
      unsigned int pw0, pw1, pw2, pw3;
      {
        float p0 = exp2_fast(fmaf(s[0][0], C2, -lm));
        float p1 = exp2_fast(fmaf(s[0][1], C2, -lm));
        float p2 = exp2_fast(fmaf(s[0][2], C2, -lm));
        float p3 = exp2_fast(fmaf(s[0][3], C2, -lm));
        pw0 = cvt_pk_bf16(p0, p1);
        pw1 = cvt_pk_bf16(p2, p3);
      }
      {
        float p0 = exp2_fast(fmaf(s[1][0], C2, -lm));
        float p1 = exp2_fast(fmaf(s[1][1], C2, -lm));
        float p2 = exp2_fast(fmaf(s[1][2], C2, -lm));
        float p3 = exp2_fast(fmaf(s[1][3], C2, -lm));
        pw2 = cvt_pk_bf16(p0, p1);
        pw3 = cvt_pk_bf16(p2, p3);
      }
      uint4v pw = {pw0, pw1, pw2, pw3};
      pb_[qi] = __builtin_bit_cast(short8, pw);
    }

    // PV: A = pb_ (in-register), B = key-permuted V^T rows, K=32 = key-half.
#pragma unroll
    for (int dt = 0; dt < 4; ++dt) {
      const int vrow = dt * 16 + rq;
      short8 v = *(const short8*)&Vs[(vrow * 64 + kh * 32 + kk8) ^ sx];
      o_acc[0][dt] = __builtin_amdgcn_mfma_f32_16x16x32_bf16(pb_[0], v, o_acc[0][dt], 0, 0, 0);
      o_acc[1][dt] = __builtin_amdgcn_mfma_f32_16x16x32_bf16(pb_[1], v, o_acc[1][dt], 0, 0, 0);
    }
    acc_l[0] = __builtin_amdgcn_mfma_f32_16x16x32_bf16(pb_[0], ones, acc_l[0], 0, 0, 0);
    acc_l[1] = __builtin_amdgcn_mfma_f32_16x16x32_bf16(pb_[1], ones, acc_l[1], 0, 0, 0);

    if (it < 63) {  // write next tile into the alternate buffer
      *(short8*)&KsB[(cur ^ 1) * 4096 + st] = kr;
      *(short8*)&VsB[(cur ^ 1) * 4096 + st] = vr;
    }
  }

  __syncthreads();  // all K-loop LDS traffic done before merge overlay
  // ---- 2-way key-half merge (kh=1 publishes, kh=0 combines + writes) ----
  float* MO = (float*)smem;            // [4 qc][32 q][64 dk]
  float* ML = (float*)(smem + 32768);  // [128 q][2] {m, l}
  if (kh == 1) {
#pragma unroll
    for (int qi = 0; qi < 2; ++qi) {
#pragma unroll
      for (int j = 0; j < 4; ++j) {
        int row = qc * 32 + qi * 16 + lg * 4 + j;
        if (rq == 0) ML[row * 2 + 1] = acc_l[qi][j];
#pragma unroll
        for (int dt = 0; dt < 4; ++dt)
          MO[(size_t)row * 64 + dt * 16 + rq] = o_acc[qi][dt][j];
      }
      if (lg == 0) ML[(qc * 32 + qi * 16 + rq) * 2] = m_run[qi];
    }
  }
  __syncthreads();
  if (kh == 0) {
#pragma unroll
    for (int qi = 0; qi < 2; ++qi) {
      float m0c[4];
#pragma unroll
      for (int j = 0; j < 4; ++j) m0c[j] = __shfl(m_run[qi], lg * 4 + j, 64);
#pragma unroll
      for (int j = 0; j < 4; ++j) {
        int row = qc * 32 + qi * 16 + lg * 4 + j;
        int r = q0 + qi * 16 + lg * 4 + j;
        float m1 = ML[row * 2 + 0], l1 = ML[row * 2 + 1];
        float mx = fmaxf(m0c[j], m1);
        float a0 = exp2_fast(m0c[j] - mx), a1 = exp2_fast(m1 - mx);
        float inv = 1.0f / (acc_l[qi][j] * a0 + l1 * a1);
#pragma unroll
        for (int dt = 0; dt < 4; ++dt) {
          float o = (o_acc[qi][dt][j] * a0 + MO[(size_t)row * 64 + dt * 16 + rq] * a1) * inv;
          Op[((size_t)b * Sc + r) * Dc + h * DKc + dt * 16 + rq] = f2bf(o);
        }
      }
    }
  }
}

// ---------------- launcher --------------------------------------------------
extern "C" void kernel_launch(void* const* d_in, const int* in_sizes, int n_in,
                              void* d_out, int out_size, void* d_ws, size_t ws_size,
                              hipStream_t stream) {
  const float* q_in = (const float*)d_in[0];
  const float* k_in = (const float*)d_in[1];
  const float* v_in = (const float*)d_in[2];
  const float* Wq = (const float*)d_in[3];
  const float* Wk = (const float*)d_in[4];
  const float* Wv = (const float*)d_in[5];
  const float* Wo = (const float*)d_in[6];

  unsigned short* qb = (unsigned short*)d_ws;   // [M,D] bf16
  unsigned short* kb = qb + (size_t)Mc * Dc;
  unsigned short* ab = kb + (size_t)Mc * Dc;
  unsigned short* vt = ab + (size_t)Mc * Dc;    // V^T (key-permuted) per b

  // batched Q/K/V projections; V slice writes vt directly (fused transpose)
  dim3 gq(Dc / 64, Mc / 128, 3);  // (8, 64, 3) = 1536 blocks
  gemm_qkv<<<gq, 256, 0, stream>>>(q_in, k_in, v_in, Wq, Wk, Wv, qb, kb, vt);

  dim3 ga(Sc / 128, Bc * Hc);  // (32, 16) = 512 blocks, 512 thr
  attn_fwd<<<ga, 512, 0, stream>>>(qb, kb, vt, ab);

  dim3 gg(Dc / 64, Mc / 128);  // (8, 64)
  gemm_out<<<gg, 256, 0, stream>>>(ab, Wo, (float*)d_out);
}

// Round 22
// 162.060 us; speedup vs baseline: 2.5828x; 1.0063x over previous
//
#include <hip/hip_runtime.h>
#include <hip/hip_bf16.h>

typedef short short8 __attribute__((ext_vector_type(8)));
typedef short short4v __attribute__((ext_vector_type(4)));
typedef float floatx4 __attribute__((ext_vector_type(4)));
typedef unsigned int uint4v __attribute__((ext_vector_type(4)));

constexpr int Bc = 2, Sc = 4096, Dc = 512, Hc = 8, DKc = 64;
constexpr int Mc = Bc * Sc;  // 8192

static __device__ __forceinline__ unsigned short f2bf(float f) {
  unsigned int u = __builtin_bit_cast(unsigned int, f);
  unsigned int rb = ((u >> 16) & 1u) + 0x7fffu;
  return (unsigned short)((u + rb) >> 16);
}
// hardware packed f32x2 -> bf16x2 (RNE), 1 instruction
static __device__ __forceinline__ unsigned int cvt_pk_bf16(float lo, float hi) {
  unsigned int r;
  asm("v_cvt_pk_bf16_f32 %0, %1, %2" : "=v"(r) : "v"(lo), "v"(hi));
  return r;
}
// 2^x, 1 instruction
static __device__ __forceinline__ float exp2_fast(float x) {
  float r;
  asm("v_exp_f32 %0, %1" : "=v"(r) : "v"(x));
  return r;
}
// NOTE (R9-R11): v_permlane16/32_swap_b32 BANNED (3 correctness failures).
// NOTE (R17): smaller attn blocks for occupancy REGRESS (work per-cell 2x).
// NOTE (R20): direct-global fragment loads REGRESS 3.8x (uncoalesced gathers
// + lambda-array scratch spill). LDS staging stays; body arrays stay local.

// ---------------- GEMM body: Y[M,N] = X[M,K] @ W[N,K]^T ----------------------
// Double-buffered; one barrier per K-iter; W_F32 casts weights during staging.
// VT_OUT writes the V projection as key-permuted transpose vt (fused).
template <int IN_F32, int OUT_F32, int W_F32, int VT_OUT>
static __device__ __forceinline__ void gemm_body(
    const void* __restrict__ Xv, const void* __restrict__ Wp,
    void* __restrict__ Yv, const int N, const int K) {
  constexpr int BM = 128, BN = 64, BK = 32, LDP = 40;
  __shared__ unsigned short As[2][BM * LDP];
  __shared__ unsigned short Bs[2][BN * LDP];
  const int tid = threadIdx.x;
  const int lane = tid & 63, wid = tid >> 6;
  const int wm = wid >> 1, wn = wid & 1;
  const int bm = blockIdx.y * BM, bn = blockIdx.x * BN;
  const int rq = lane & 15, lg = lane >> 4, kk8 = lg * 8;
  const int sr = tid >> 1, sc = (tid & 1) * 16;
  const int brow = tid >> 2, bc8 = (tid & 3) * 8;

  floatx4 acc[4][2] = {};

  float a32[16];
  short8 a16[2];
  float b32[8];
  short8 b16;

  auto load_tile = [&](int k0) {
    if (IN_F32) {
      const float* src = (const float*)Xv + (size_t)(bm + sr) * K + k0 + sc;
#pragma unroll
      for (int i = 0; i < 4; ++i) {
        float4 v = *(const float4*)(src + i * 4);
        a32[4 * i + 0] = v.x; a32[4 * i + 1] = v.y;
        a32[4 * i + 2] = v.z; a32[4 * i + 3] = v.w;
      }
    } else {
      const unsigned short* src =
          (const unsigned short*)Xv + (size_t)(bm + sr) * K + k0 + sc;
      a16[0] = *(const short8*)src;
      a16[1] = *(const short8*)(src + 8);
    }
    if (W_F32) {
      const float* wsrc = (const float*)Wp + (size_t)(bn + brow) * K + k0 + bc8;
#pragma unroll
      for (int i = 0; i < 2; ++i) {
        float4 v = *(const float4*)(wsrc + i * 4);
        b32[4 * i + 0] = v.x; b32[4 * i + 1] = v.y;
        b32[4 * i + 2] = v.z; b32[4 * i + 3] = v.w;
      }
    } else {
      b16 = *(const short8*)((const unsigned short*)Wp +
                             (size_t)(bn + brow) * K + k0 + bc8);
    }
  };
  auto store_tile = [&](int bf) {
    if (IN_F32) {
      unsigned int t2[8];
#pragma unroll
      for (int i = 0; i < 8; ++i) t2[i] = cvt_pk_bf16(a32[2 * i], a32[2 * i + 1]);
      uint4v u0 = {t2[0], t2[1], t2[2], t2[3]};
      uint4v u1 = {t2[4], t2[5], t2[6], t2[7]};
      *(uint4v*)&As[bf][sr * LDP + sc] = u0;
      *(uint4v*)&As[bf][sr * LDP + sc + 8] = u1;
    } else {
      *(short8*)&As[bf][sr * LDP + sc] = a16[0];
      *(short8*)&As[bf][sr * LDP + sc + 8] = a16[1];
    }
    if (W_F32) {
      unsigned int t2[4];
#pragma unroll
      for (int i = 0; i < 4; ++i) t2[i] = cvt_pk_bf16(b32[2 * i], b32[2 * i + 1]);
      uint4v u = {t2[0], t2[1], t2[2], t2[3]};
      *(uint4v*)&Bs[bf][brow * LDP + bc8] = u;
    } else {
      *(short8*)&Bs[bf][brow * LDP + bc8] = b16;
    }
  };

  load_tile(0);
  store_tile(0);

  const int NK = K / BK;  // 16
  for (int it = 0; it < NK; ++it) {
    const int cur = it & 1;
    __syncthreads();

    if (it < NK - 1) load_tile((it + 1) * BK);

    short8 af[4], bfr[2];
#pragma unroll
    for (int mi = 0; mi < 4; ++mi)
      af[mi] = *(const short8*)&As[cur][(wm * 64 + mi * 16 + rq) * LDP + kk8];
#pragma unroll
    for (int ni = 0; ni < 2; ++ni)
      bfr[ni] = *(const short8*)&Bs[cur][(wn * 32 + ni * 16 + rq) * LDP + kk8];
#pragma unroll
    for (int mi = 0; mi < 4; ++mi)
#pragma unroll
      for (int ni = 0; ni < 2; ++ni)
        acc[mi][ni] = __builtin_amdgcn_mfma_f32_16x16x32_bf16(
            af[mi], bfr[ni], acc[mi][ni], 0, 0, 0);

    if (it < NK - 1) store_tile(cur ^ 1);
  }

  if (VT_OUT) {
    // fused transpose + sigma-permute epilogue (V projection -> vt).
    __syncthreads();
    unsigned short* T = (unsigned short*)As;  // [64 c][136] shorts
    const int bb = bm >> 12;
    const int sl0 = bm & 4095;
#pragma unroll
    for (int mi = 0; mi < 4; ++mi) {
      const int spb = wm * 64 + (mi >> 1) * 32 + lg * 8 + (mi & 1) * 4;
#pragma unroll
      for (int ni = 0; ni < 2; ++ni) {
        const int c = wn * 32 + ni * 16 + rq;
#pragma unroll
        for (int j = 0; j < 4; ++j)
          T[c * 136 + spb + j] = f2bf(acc[mi][ni][j]);
      }
    }
    __syncthreads();
    const int c = tid >> 2, seg = (tid & 3) * 32;
    unsigned short* dst = (unsigned short*)Yv +
        ((size_t)bb * Dc + bn + c) * Sc + sl0 + seg;
#pragma unroll
    for (int u = 0; u < 4; ++u)
      *(short8*)(dst + u * 8) = *(const short8*)&T[c * 136 + seg + u * 8];
  } else {
#pragma unroll
    for (int mi = 0; mi < 4; ++mi)
#pragma unroll
      for (int ni = 0; ni < 2; ++ni)
#pragma unroll
        for (int j = 0; j < 4; ++j) {
          int r = bm + wm * 64 + mi * 16 + lg * 4 + j;
          int c = bn + wn * 32 + ni * 16 + rq;
          float v = acc[mi][ni][j];
          if (OUT_F32)
            ((float*)Yv)[(size_t)r * N + c] = v;
          else
            ((unsigned short*)Yv)[(size_t)r * N + c] = f2bf(v);
        }
  }
}

// batched Q/K/V projection: blockIdx.z selects input/weight/output.
__global__ __launch_bounds__(256) void gemm_qkv(
    const float* __restrict__ xq, const float* __restrict__ xk,
    const float* __restrict__ xv, const float* __restrict__ wq,
    const float* __restrict__ wk, const float* __restrict__ wv,
    unsigned short* __restrict__ yq, unsigned short* __restrict__ yk,
    unsigned short* __restrict__ vt) {
  const int z = blockIdx.z;
  if (z == 2) {
    gemm_body<1, 0, 1, 1>(xv, wv, vt, Dc, Dc);
  } else {
    const float* X = (z == 0) ? xq : xk;
    const float* W = (z == 0) ? wq : wk;
    unsigned short* Y = (z == 0) ? yq : yk;
    gemm_body<1, 0, 1, 0>(X, W, Y, Dc, Dc);
  }
}

// output projection: bf16 input, f32 weight, f32 output.
__global__ __launch_bounds__(256) void gemm_out(
    const unsigned short* __restrict__ x, const float* __restrict__ w,
    float* __restrict__ y) {
  gemm_body<0, 1, 1, 0>(x, w, y, Dc, Dc);
}

// ---------------- flash attention --------------------------------------------
// R19 body (verified 95.5us) with R22's halved-barrier staging: two 64-key
// subtiles staged per barrier period (KB=128 staging, KB=64 compute). 32
// barriers instead of 64; 4 staged loads in flight per period (deeper MLP).
// Inner compute body is R19 verbatim, unrolled over sub (all frag arrays
// local — R20 lesson). 128 q-rows, 8 waves = 4 q-chunks x 2 key-halves;
// swapped QK^T; defer-max THR=8; in-register P via sigma key-permute; l on
// the MFMA pipe; XCD block swizzle.
__global__ __launch_bounds__(512, 4) void attn_fwd(
    const unsigned short* __restrict__ Qp, const unsigned short* __restrict__ Kp,
    const unsigned short* __restrict__ Vtp, unsigned short* __restrict__ Op) {
  // LDS: Ks [0,32768) 2buf x 2sub x [64][64] swz; Vs [32768,65536) same.
  // Merge overlay: MO f32 [128 q][64 dk] @0 (32KB), ML f32 [128][2] @32768.
  __shared__ unsigned char smem[65536];
  unsigned short* KsB = (unsigned short*)smem;            // [2][2][4096]
  unsigned short* VsB = (unsigned short*)(smem + 32768);  // [2][2][4096]

  const int tid = threadIdx.x, lane = tid & 63, wid = tid >> 6;
  const int qc = wid >> 1, kh = wid & 1;
  // XCD swizzle: logical tile from permuted flat id (bijective, 512%8==0)
  const int F = blockIdx.y * 32 + blockIdx.x;   // gridDim.x == 32
  const int L = (F & 7) * 64 + (F >> 3);
  const int bh = L >> 5, qt = L & 31;
  const int b = bh >> 3, h = bh & 7;
  const int q0 = qt * 128 + qc * 32;
  const int rq = lane & 15, lg = lane >> 4, kk8 = lg * 8;

  const unsigned short* Qb = Qp + ((size_t)b * Sc) * Dc + h * DKc;
  const unsigned short* Kb = Kp + ((size_t)b * Sc) * Dc + h * DKc;
  const unsigned short* Vh = Vtp + ((size_t)b * Dc + h * DKc) * Sc;

  // Q as B-fragment: col = lane&15 = q-local, k = (lane>>4)*8+j
  short8 qa[2][2];
#pragma unroll
  for (int qi = 0; qi < 2; ++qi)
#pragma unroll
    for (int c = 0; c < 2; ++c)
      qa[qi][c] = *(const short8*)(Qb + (size_t)(q0 + qi * 16 + rq) * Dc + c * 32 + kk8);

  floatx4 o_acc[2][4] = {};
  floatx4 acc_l[2] = {};              // l via MFMA: row q = qi*16+lg*4+j
  float m_run[2] = {-1e30f, -1e30f};  // per-lane (q = lane&15), log2 domain

  short8 ones;
#pragma unroll
  for (int j = 0; j < 8; ++j) ones[j] = (short)0x3F80;  // bf16 1.0

  const float C2 = 0.18033688f;   // (1/sqrt(64)) * log2(e)
  const float THR = 8.0f;         // defer-max bound: P <= 2^8

  // staging: per barrier period each thread stages one short8 into each of
  // the 4 subtile arrays (K sub0/sub1, V sub0/sub1); XOR swizzle per subtile
  const int sr = tid >> 3, sc8 = (tid & 7) * 8;
  const int st = (sr * 64 + sc8) ^ ((sr & 7) << 3);
  const int sx = (rq & 7) << 3;

  // prologue: key tile pair 0 -> regs -> buf0
  short8 kr0 = *(const short8*)(Kb + (size_t)sr * Dc + sc8);
  short8 kr1 = *(const short8*)(Kb + (size_t)(64 + sr) * Dc + sc8);
  short8 vr0 = *(const short8*)(Vh + (size_t)sr * Sc + sc8);
  short8 vr1 = *(const short8*)(Vh + (size_t)sr * Sc + 64 + sc8);
  *(short8*)&KsB[st] = kr0;
  *(short8*)&KsB[4096 + st] = kr1;
  *(short8*)&VsB[st] = vr0;
  *(short8*)&VsB[4096 + st] = vr1;

  for (int it = 0; it < 32; ++it) {
    const int cur = it & 1;
    __syncthreads();  // buf[cur] writes visible; buf[cur^1] reads done

    if (it < 31) {  // issue next 128-key tile's loads; land during compute
      const int kn = (it + 1) * 128;
      kr0 = *(const short8*)(Kb + (size_t)(kn + sr) * Dc + sc8);
      kr1 = *(const short8*)(Kb + (size_t)(kn + 64 + sr) * Dc + sc8);
      vr0 = *(const short8*)(Vh + (size_t)sr * Sc + kn + sc8);
      vr1 = *(const short8*)(Vh + (size_t)sr * Sc + kn + 64 + sc8);
    }

#pragma unroll
    for (int sub = 0; sub < 2; ++sub) {
      const unsigned short* Ks = KsB + cur * 8192 + sub * 4096;
      const unsigned short* Vs = VsB + cur * 8192 + sub * 4096;

      // K A-frags for this wave's key-half (shared across both q-subtiles)
      short8 ka[2][2];
#pragma unroll
      for (int ks = 0; ks < 2; ++ks)
#pragma unroll
        for (int c = 0; c < 2; ++c) {
          const int row = kh * 32 + ks * 16 + rq;
          ka[ks][c] = *(const short8*)&Ks[(row * 64 + c * 32 + kk8) ^ sx];
        }

      short8 pb_[2];  // per-qi PV A-frags, built fully in-register
#pragma unroll
      for (int qi = 0; qi < 2; ++qi) {
        // swapped QK^T: s[ks][j] = S^T[key = kh*32+ks*16+lg*4+j][q = rq]
        floatx4 s[2] = {};
#pragma unroll
        for (int ks = 0; ks < 2; ++ks) {
          s[ks] = __builtin_amdgcn_mfma_f32_16x16x32_bf16(ka[ks][0], qa[qi][0], s[ks], 0, 0, 0);
          s[ks] = __builtin_amdgcn_mfma_f32_16x16x32_bf16(ka[ks][1], qa[qi][1], s[ks], 0, 0, 0);
        }
        // per-lane partial max over own 8 keys: max3-shaped tree
        float t1 = fmaxf(fmaxf(s[0][0], s[0][1]), s[0][2]);
        float t2 = fmaxf(fmaxf(s[0][3], s[1][0]), s[1][1]);
        float t3 = fmaxf(fmaxf(s[1][2], s[1][3]), t1);
        float tp = fmaxf(t3, t2) * C2;

        if (__any(tp > m_run[qi] + THR)) {  // rare: bound would be exceeded
          float tm = tp;
          tm = fmaxf(tm, __shfl_xor(tm, 16, 64));
          tm = fmaxf(tm, __shfl_xor(tm, 32, 64));
          if (__any(tm > m_run[qi])) {
            float mn = fmaxf(m_run[qi], tm);
            float scf = exp2_fast(m_run[qi] - mn);
            m_run[qi] = mn;
            float sc_c[4];
#pragma unroll
            for (int j = 0; j < 4; ++j) sc_c[j] = __shfl(scf, lg * 4 + j, 64);
#pragma unroll
            for (int j = 0; j < 4; ++j) {
              acc_l[qi][j] *= sc_c[j];
#pragma unroll
              for (int dt = 0; dt < 4; ++dt) o_acc[qi][dt][j] *= sc_c[j];
            }
          }
        }

        // P = 2^(s*C2 - m), packed in A-frag slot order (sigma-matched)
        const float lm = m_run[qi];
        unsigned int pw0, pw1, pw2, pw3;
        {
          float p0 = exp2_fast(fmaf(s[0][0], C2, -lm));
          float p1 = exp2_fast(fmaf(s[0][1], C2, -lm));
          float p2 = exp2_fast(fmaf(s[0][2], C2, -lm));
          float p3 = exp2_fast(fmaf(s[0][3], C2, -lm));
          pw0 = cvt_pk_bf16(p0, p1);
          pw1 = cvt_pk_bf16(p2, p3);
        }
        {
          float p0 = exp2_fast(fmaf(s[1][0], C2, -lm));
          float p1 = exp2_fast(fmaf(s[1][1], C2, -lm));
          float p2 = exp2_fast(fmaf(s[1][2], C2, -lm));
          float p3 = exp2_fast(fmaf(s[1][3], C2, -lm));
          pw2 = cvt_pk_bf16(p0, p1);
          pw3 = cvt_pk_bf16(p2, p3);
        }
        uint4v pw = {pw0, pw1, pw2, pw3};
        pb_[qi] = __builtin_bit_cast(short8, pw);
      }

      // PV: A = pb_ (in-register), B = key-permuted V^T rows, K=32 = key-half.
#pragma unroll
      for (int dt = 0; dt < 4; ++dt) {
        const int vrow = dt * 16 + rq;
        short8 v = *(const short8*)&Vs[(vrow * 64 + kh * 32 + kk8) ^ sx];
        o_acc[0][dt] = __builtin_amdgcn_mfma_f32_16x16x32_bf16(pb_[0], v, o_acc[0][dt], 0, 0, 0);
        o_acc[1][dt] = __builtin_amdgcn_mfma_f32_16x16x32_bf16(pb_[1], v, o_acc[1][dt], 0, 0, 0);
      }
      acc_l[0] = __builtin_amdgcn_mfma_f32_16x16x32_bf16(pb_[0], ones, acc_l[0], 0, 0, 0);
      acc_l[1] = __builtin_amdgcn_mfma_f32_16x16x32_bf16(pb_[1], ones, acc_l[1], 0, 0, 0);
    }

    if (it < 31) {  // write next tile pair into the alternate buffer
      *(short8*)&KsB[(cur ^ 1) * 8192 + st] = kr0;
      *(short8*)&KsB[(cur ^ 1) * 8192 + 4096 + st] = kr1;
      *(short8*)&VsB[(cur ^ 1) * 8192 + st] = vr0;
      *(short8*)&VsB[(cur ^ 1) * 8192 + 4096 + st] = vr1;
    }
  }

  __syncthreads();  // all K-loop LDS traffic done before merge overlay
  // ---- 2-way key-half merge (kh=1 publishes, kh=0 combines + writes) ----
  float* MO = (float*)smem;            // [4 qc][32 q][64 dk]
  float* ML = (float*)(smem + 32768);  // [128 q][2] {m, l}
  if (kh == 1) {
#pragma unroll
    for (int qi = 0; qi < 2; ++qi) {
#pragma unroll
      for (int j = 0; j < 4; ++j) {
        int row = qc * 32 + qi * 16 + lg * 4 + j;
        if (rq == 0) ML[row * 2 + 1] = acc_l[qi][j];
#pragma unroll
        for (int dt = 0; dt < 4; ++dt)
          MO[(size_t)row * 64 + dt * 16 + rq] = o_acc[qi][dt][j];
      }
      if (lg == 0) ML[(qc * 32 + qi * 16 + rq) * 2] = m_run[qi];
    }
  }
  __syncthreads();
  if (kh == 0) {
#pragma unroll
    for (int qi = 0; qi < 2; ++qi) {
      float m0c[4];
#pragma unroll
      for (int j = 0; j < 4; ++j) m0c[j] = __shfl(m_run[qi], lg * 4 + j, 64);
#pragma unroll
      for (int j = 0; j < 4; ++j) {
        int row = qc * 32 + qi * 16 + lg * 4 + j;
        int r = q0 + qi * 16 + lg * 4 + j;
        float m1 = ML[row * 2 + 0], l1 = ML[row * 2 + 1];
        float mx = fmaxf(m0c[j], m1);
        float a0 = exp2_fast(m0c[j] - mx), a1 = exp2_fast(m1 - mx);
        float inv = 1.0f / (acc_l[qi][j] * a0 + l1 * a1);
#pragma unroll
        for (int dt = 0; dt < 4; ++dt) {
          float o = (o_acc[qi][dt][j] * a0 + MO[(size_t)row * 64 + dt * 16 + rq] * a1) * inv;
          Op[((size_t)b * Sc + r) * Dc + h * DKc + dt * 16 + rq] = f2bf(o);
        }
      }
    }
  }
}

// ---------------- launcher --------------------------------------------------
extern "C" void kernel_launch(void* const* d_in, const int* in_sizes, int n_in,
                              void* d_out, int out_size, void* d_ws, size_t ws_size,
                              hipStream_t stream) {
  const float* q_in = (const float*)d_in[0];
  const float* k_in = (const float*)d_in[1];
  const float* v_in = (const float*)d_in[2];
  const float* Wq = (const float*)d_in[3];
  const float* Wk = (const float*)d_in[4];
  const float* Wv = (const float*)d_in[5];
  const float* Wo = (const float*)d_in[6];

  unsigned short* qb = (unsigned short*)d_ws;   // [M,D] bf16
  unsigned short* kb = qb + (size_t)Mc * Dc;
  unsigned short* ab = kb + (size_t)Mc * Dc;
  unsigned short* vt = ab + (size_t)Mc * Dc;    // V^T (key-permuted) per b

  // batched Q/K/V projections; V slice writes vt directly (fused transpose)
  dim3 gq(Dc / 64, Mc / 128, 3);  // (8, 64, 3) = 1536 blocks
  gemm_qkv<<<gq, 256, 0, stream>>>(q_in, k_in, v_in, Wq, Wk, Wv, qb, kb, vt);

  dim3 ga(Sc / 128, Bc * Hc);  // (32, 16) = 512 blocks, 512 thr
  attn_fwd<<<ga, 512, 0, stream>>>(qb, kb, vt, ab);

  dim3 gg(Dc / 64, Mc / 128);  // (8, 64)
  gemm_out<<<gg, 256, 0, stream>>>(ab, Wo, (float*)d_out);
}